// Round 5
// baseline (36.906 us; speedup 1.0000x reference)
//
#include <hip/hip_runtime.h>

// Tensorized (tensor-train) embedding. vocab 32000 = 8*10*20*20, out 768,
// ranks (1,16,16,16,1), B = 32768 tokens, fp32 out.
//
// G01[c01][a][r2]  c01 = idx/400  (80 combos  x 256 floats =  80 KB)
// G23[c23][r2][mc] c23 = idx%400  (400 combos x 768 floats = 1.2 MB)
// out[tok][a*48+mc] = sum_r2 G01[a][r2] * G23[r2][mc]
//
// 2-kernel pipeline: (A) build tables (LDS-staged core reads); (B) streaming
// main: each wave owns 8 consecutive tokens, double-buffered 3KB G23 slice in
// wave-private LDS (T14 issue-early/write-late). Lane owns output float4
// slots {lane, lane+64, lane+128} -> all 3 global stores per token are
// perfectly contiguous 1KB wave-stores (fill-kernel write pattern).

#define NTOK   32768
#define TPW    8                              // tokens per wave
#define G01_BYTES  (80 * 256 * 4)             // 81920
#define G23_BYTES  (400 * 768 * 4)            // 1228800
#define TBL_BYTES  (G01_BYTES + G23_BYTES)    // 1310720

#define FMA4(A, S, V) { (A).x += (S)*(V).x; (A).y += (S)*(V).y; \
                        (A).z += (S)*(V).z; (A).w += (S)*(V).w; }

// ---- kernel A: pairwise contraction tables (480 blocks) ----
__global__ __launch_bounds__(256) void build_tables(const float* __restrict__ core0,
                                                    const float* __restrict__ core1,
                                                    const float* __restrict__ core2,
                                                    const float* __restrict__ core3,
                                                    float* __restrict__ g01,
                                                    float* __restrict__ g23) {
    __shared__ float s2[1536];              // [r2][m2][r3] slice of core2 (d2 fixed)
    __shared__ float s3[128];               // [r3][m3]     slice of core3 (d3 fixed)
    __shared__ float s1[1024];              // [r1][m1][r2] slice of core1 (d1 fixed)
    __shared__ float s0[64];                // [a0][r1]     slice of core0 (d0 fixed)
    int b = blockIdx.x;
    int t = threadIdx.x;
    if (b < 400) {                          // G23 combo c23 = d2*20+d3
        int d2 = b / 20, d3 = b % 20;
#pragma unroll
        for (int i = 0; i < 6; ++i) {       // core2 slice: 1536 floats, coalesced
            int f = t + i * 256;
            int r2 = f / 96, j = f - r2 * 96;        // j = m2*16+r3
            s2[f] = core2[r2 * 1920 + d2 * 96 + j];  // [16,20,6,16]
        }
        if (t < 128)                        // core3 slice: 128 floats
            s3[t] = core3[(t >> 3) * 160 + d3 * 8 + (t & 7)];   // [16,20,8,1]
        __syncthreads();
#pragma unroll
        for (int i = 0; i < 3; ++i) {
            int f = t + i * 256;            // [0,768) = r2(16) * mc(48)
            int r2 = f / 48, mc = f - r2 * 48;
            int m2 = mc >> 3, m3 = mc & 7;
            float acc = 0.f;
#pragma unroll
            for (int r3 = 0; r3 < 16; ++r3)
                acc += s2[r2 * 96 + m2 * 16 + r3] * s3[r3 * 8 + m3];
            g23[b * 768 + f] = acc;
        }
    } else {                                // G01 combo c01 = d0*10+d1
        int combo = b - 400;                // 0..79
        int d0 = combo / 10, d1 = combo % 10;
#pragma unroll
        for (int i = 0; i < 4; ++i) {       // core1 slice: 1024 floats, coalesced
            int f = t + i * 256;
            int r1 = f >> 6, j = f & 63;             // j = m1*16+r2
            s1[f] = core1[r1 * 640 + d1 * 64 + j];   // [16,10,4,16]
        }
        if (t < 64)
            s0[t] = core0[d0 * 64 + t];              // [1,8,4,16]
        __syncthreads();
        int a = t >> 4, r2 = t & 15;
        int a0 = a >> 2, m1 = a & 3;
        float acc = 0.f;
#pragma unroll
        for (int r1 = 0; r1 < 16; ++r1)
            acc += s0[a0 * 16 + r1] * s1[r1 * 64 + m1 * 16 + r2];
        g01[combo * 256 + t] = acc;
    }
}

// ---- kernel B: token-order streaming main, contiguous stores ----
__global__ __launch_bounds__(256) void te_stream(const int* __restrict__ x,
                                                 const float* __restrict__ g01,
                                                 const float* __restrict__ g23,
                                                 float* __restrict__ out) {
    __shared__ float lds[4][2][768];        // [wave][buf][slice] = 24 KB
    const int wave = threadIdx.x >> 6;
    const int lane = threadIdx.x & 63;
    const int tok0 = (blockIdx.x * 4 + wave) * TPW;
    float* __restrict__ b0 = lds[wave][0];
    float* __restrict__ b1 = lds[wave][1];

    // lane's three output float4 slots (contiguous per wave-store)
    const int sl[3] = {lane, lane + 64, lane + 128};
    int ap[3], cp[3];                       // slot -> (G1 row a, col group c)
#pragma unroll
    for (int p = 0; p < 3; ++p) { ap[p] = sl[p] / 12; cp[p] = sl[p] - ap[p] * 12; }

    // all 8 token indices up front (two coalesced int4 loads)
    int4 xa = ((const int4*)(x + tok0))[0];
    int4 xb = ((const int4*)(x + tok0))[1];
    int idxs[TPW] = {xa.x, xa.y, xa.z, xa.w, xb.x, xb.y, xb.z, xb.w};

    float s[3][16];                         // current token's 3 G1 rows
    // prologue: stage token 0
    {
        const float4* G2 = (const float4*)(g23 + (idxs[0] % 400) * 768);
        float4 t0 = G2[lane], t1 = G2[lane + 64], t2 = G2[lane + 128];
        ((float4*)b0)[lane] = t0;
        ((float4*)b0)[lane + 64] = t1;
        ((float4*)b0)[lane + 128] = t2;
        const float4* G1 = (const float4*)(g01 + (idxs[0] / 400) * 256);
#pragma unroll
        for (int p = 0; p < 3; ++p)
#pragma unroll
            for (int k = 0; k < 4; ++k) {
                float4 r = G1[ap[p] * 4 + k];
                s[p][k * 4 + 0] = r.x; s[p][k * 4 + 1] = r.y;
                s[p][k * 4 + 2] = r.z; s[p][k * 4 + 3] = r.w;
            }
    }

#pragma unroll
    for (int t = 0; t < TPW; ++t) {
        float* cur = (t & 1) ? b1 : b0;
        float* nxt = (t & 1) ? b0 : b1;

        // (1) issue next token's global loads EARLY (latency hides under compute)
        float4 n0, n1, n2;
        float m[3][16];
        if (t + 1 < TPW) {
            const float4* G2n = (const float4*)(g23 + (idxs[t + 1] % 400) * 768);
            n0 = G2n[lane]; n1 = G2n[lane + 64]; n2 = G2n[lane + 128];
            const float4* G1n = (const float4*)(g01 + (idxs[t + 1] / 400) * 256);
#pragma unroll
            for (int p = 0; p < 3; ++p)
#pragma unroll
                for (int k = 0; k < 4; ++k) {
                    float4 r = G1n[ap[p] * 4 + k];
                    m[p][k * 4 + 0] = r.x; m[p][k * 4 + 1] = r.y;
                    m[p][k * 4 + 2] = r.z; m[p][k * 4 + 3] = r.w;
                }
        }

        // (2) compute token t from LDS (48 ds_read_b128, <=2-way bank alias)
        float4 acc0 = {0.f,0.f,0.f,0.f}, acc1 = {0.f,0.f,0.f,0.f}, acc2 = {0.f,0.f,0.f,0.f};
#pragma unroll
        for (int r2 = 0; r2 < 16; ++r2) {
            float4 v0 = *(const float4*)(cur + r2 * 48 + cp[0] * 4);
            float4 v1 = *(const float4*)(cur + r2 * 48 + cp[1] * 4);
            float4 v2 = *(const float4*)(cur + r2 * 48 + cp[2] * 4);
            FMA4(acc0, s[0][r2], v0);
            FMA4(acc1, s[1][r2], v1);
            FMA4(acc2, s[2][r2], v2);
        }

        // (3) store token t: three contiguous 1KB wave-stores
        float4* o4 = (float4*)(out + (size_t)(tok0 + t) * 768);
        o4[lane]       = acc0;
        o4[lane + 64]  = acc1;
        o4[lane + 128] = acc2;

        // (4) write next token's slice into the other buffer LATE
        if (t + 1 < TPW) {
            ((float4*)nxt)[lane] = n0;
            ((float4*)nxt)[lane + 64] = n1;
            ((float4*)nxt)[lane + 128] = n2;
#pragma unroll
            for (int p = 0; p < 3; ++p)
#pragma unroll
                for (int k = 0; k < 16; ++k)
                    s[p][k] = m[p][k];
        }
    }
}

// ---- fallback ----
__global__ void te_direct(const int* __restrict__ x,
                          const float* __restrict__ core0,
                          const float* __restrict__ core1,
                          const float* __restrict__ core2,
                          const float* __restrict__ core3,
                          float* __restrict__ out) {
    int tok = blockIdx.x;
    int lane = threadIdx.x;
    int idx = x[tok];
    int d0 = idx / 4000;
    int rem = idx - d0 * 4000;
    int d1 = rem / 400;
    rem -= d1 * 400;
    int d2 = rem / 20;
    int d3 = rem - d2 * 20;
    float* o = out + (size_t)tok * 768;
    for (int p = 0; p < 3; ++p) {
        int base = (p * 64 + lane) * 4;
        int a = base / 48;
        int mc = base - a * 48;
        int a0 = a >> 2, m1 = a & 3;
        float s[16];
#pragma unroll
        for (int r2 = 0; r2 < 16; ++r2) {
            float acc = 0.f;
            for (int r1 = 0; r1 < 16; ++r1)
                acc += core0[(d0 * 4 + a0) * 16 + r1] *
                       core1[((r1 * 10 + d1) * 4 + m1) * 16 + r2];
            s[r2] = acc;
        }
        float4 accv = {0.f, 0.f, 0.f, 0.f};
        float* accp = (float*)&accv;
        for (int j = 0; j < 4; ++j) {
            int mcj = mc + j;
            int m2 = mcj >> 3, m3 = mcj & 7;
            float tt = 0.f;
            for (int r2 = 0; r2 < 16; ++r2) {
                float g = 0.f;
                for (int r3 = 0; r3 < 16; ++r3)
                    g += core2[((r2 * 20 + d2) * 6 + m2) * 16 + r3] *
                         core3[(r3 * 20 + d3) * 8 + m3];
                tt += s[r2] * g;
            }
            accp[j] = tt;
        }
        *(float4*)(o + base) = accv;
    }
}

extern "C" void kernel_launch(void* const* d_in, const int* in_sizes, int n_in,
                              void* d_out, int out_size, void* d_ws, size_t ws_size,
                              hipStream_t stream) {
    const int*   x     = (const int*)d_in[0];
    const float* core0 = (const float*)d_in[1];
    const float* core1 = (const float*)d_in[2];
    const float* core2 = (const float*)d_in[3];
    const float* core3 = (const float*)d_in[4];
    float* out = (float*)d_out;

    if (ws_size >= (size_t)TBL_BYTES) {
        float* g01 = (float*)d_ws;
        float* g23 = (float*)((char*)d_ws + G01_BYTES);
        build_tables<<<480, 256, 0, stream>>>(core0, core1, core2, core3, g01, g23);
        // 1024 blocks x 4 waves x 8 tokens = 32768 exactly
        te_stream<<<NTOK / (4 * TPW), 256, 0, stream>>>(x, g01, g23, out);
    } else {
        te_direct<<<NTOK, 64, 0, stream>>>(x, core0, core1, core2, core3, out);
    }
}

// Round 6
// 36.593 us; speedup vs baseline: 1.0086x; 1.0086x over previous
//
#include <hip/hip_runtime.h>

// Tensorized (tensor-train) embedding. vocab 32000 = 8*10*20*20, out 768,
// ranks (1,16,16,16,1), B = 32768 tokens, fp32 out.
//
// G01[c01][a][r2]  c01 = idx/400  (80 combos  x 256 floats =  80 KB)
// G23[c23][r2][mc] c23 = idx%400  (400 combos x 768 floats = 1.2 MB)
// out[tok][a*48+mc] = sum_r2 G01[a][r2] * G23[r2][mc]
//
// (A) build tables (LDS-staged core reads); (B) streaming main (R4 layout:
// lane owns row a=lane>>2, col group q=lane&3; wave owns 8 consecutive
// tokens, double-buffered 3KB G23 slice in wave-private LDS, T14
// issue-early/write-late). NEW: non-temporal output stores so the 100MB
// write stream does not evict the 1.2MB G23 table from L2.

#define NTOK   32768
#define TPW    8                              // tokens per wave
#define G01_BYTES  (80 * 256 * 4)             // 81920
#define G23_BYTES  (400 * 768 * 4)            // 1228800
#define TBL_BYTES  (G01_BYTES + G23_BYTES)    // 1310720

typedef __attribute__((ext_vector_type(4))) float f32x4;

#define FMA4(A, S, V) { (A).x += (S)*(V).x; (A).y += (S)*(V).y; \
                        (A).z += (S)*(V).z; (A).w += (S)*(V).w; }

#define NTSTORE(val, ptr) __builtin_nontemporal_store(*(const f32x4*)&(val), (f32x4*)(ptr))

// ---- kernel A: pairwise contraction tables (480 blocks, LDS-staged) ----
__global__ __launch_bounds__(256) void build_tables(const float* __restrict__ core0,
                                                    const float* __restrict__ core1,
                                                    const float* __restrict__ core2,
                                                    const float* __restrict__ core3,
                                                    float* __restrict__ g01,
                                                    float* __restrict__ g23) {
    __shared__ float s2[1536];              // [r2][m2][r3] slice of core2 (d2 fixed)
    __shared__ float s3[128];               // [r3][m3]     slice of core3 (d3 fixed)
    __shared__ float s1[1024];              // [r1][m1][r2] slice of core1 (d1 fixed)
    __shared__ float s0[64];                // [a0][r1]     slice of core0 (d0 fixed)
    int b = blockIdx.x;
    int t = threadIdx.x;
    if (b < 400) {                          // G23 combo c23 = d2*20+d3
        int d2 = b / 20, d3 = b % 20;
#pragma unroll
        for (int i = 0; i < 6; ++i) {       // core2 slice: 1536 floats, coalesced
            int f = t + i * 256;
            int r2 = f / 96, j = f - r2 * 96;        // j = m2*16+r3
            s2[f] = core2[r2 * 1920 + d2 * 96 + j];  // [16,20,6,16]
        }
        if (t < 128)                        // core3 slice: 128 floats
            s3[t] = core3[(t >> 3) * 160 + d3 * 8 + (t & 7)];   // [16,20,8,1]
        __syncthreads();
#pragma unroll
        for (int i = 0; i < 3; ++i) {
            int f = t + i * 256;            // [0,768) = r2(16) * mc(48)
            int r2 = f / 48, mc = f - r2 * 48;
            int m2 = mc >> 3, m3 = mc & 7;
            float acc = 0.f;
#pragma unroll
            for (int r3 = 0; r3 < 16; ++r3)
                acc += s2[r2 * 96 + m2 * 16 + r3] * s3[r3 * 8 + m3];
            g23[b * 768 + f] = acc;
        }
    } else {                                // G01 combo c01 = d0*10+d1
        int combo = b - 400;                // 0..79
        int d0 = combo / 10, d1 = combo % 10;
#pragma unroll
        for (int i = 0; i < 4; ++i) {       // core1 slice: 1024 floats, coalesced
            int f = t + i * 256;
            int r1 = f >> 6, j = f & 63;             // j = m1*16+r2
            s1[f] = core1[r1 * 640 + d1 * 64 + j];   // [16,10,4,16]
        }
        if (t < 64)
            s0[t] = core0[d0 * 64 + t];              // [1,8,4,16]
        __syncthreads();
        int a = t >> 4, r2 = t & 15;
        int a0 = a >> 2, m1 = a & 3;
        float acc = 0.f;
#pragma unroll
        for (int r1 = 0; r1 < 16; ++r1)
            acc += s0[a0 * 16 + r1] * s1[r1 * 64 + m1 * 16 + r2];
        g01[combo * 256 + t] = acc;
    }
}

// ---- kernel B: token-order streaming main (R4 layout + nt stores) ----
__global__ __launch_bounds__(256) void te_stream(const int* __restrict__ x,
                                                 const float* __restrict__ g01,
                                                 const float* __restrict__ g23,
                                                 float* __restrict__ out) {
    __shared__ float lds[4][2][768];        // [wave][buf][slice] = 24 KB
    const int wave = threadIdx.x >> 6;
    const int lane = threadIdx.x & 63;
    const int tok0 = (blockIdx.x * 4 + wave) * TPW;
    const int a = lane >> 2, q = lane & 3;  // lane owns row a, col group q
    float* __restrict__ b0 = lds[wave][0];
    float* __restrict__ b1 = lds[wave][1];

    // all 8 token indices up front (two coalesced int4 loads)
    int4 xa = ((const int4*)(x + tok0))[0];
    int4 xb = ((const int4*)(x + tok0))[1];
    int idxs[TPW] = {xa.x, xa.y, xa.z, xa.w, xb.x, xb.y, xb.z, xb.w};

    // prologue: stage token 0 into buf0, G1 row into regs
    {
        const float4* G2 = (const float4*)(g23 + (idxs[0] % 400) * 768);
        float4 t0 = G2[lane], t1 = G2[lane + 64], t2 = G2[lane + 128];
        ((float4*)b0)[lane] = t0;
        ((float4*)b0)[lane + 64] = t1;
        ((float4*)b0)[lane + 128] = t2;
    }
    const float4* g1p = (const float4*)(g01 + (idxs[0] / 400) * 256 + a * 16);
    float4 s0 = g1p[0], s1 = g1p[1], s2 = g1p[2], s3 = g1p[3];

#pragma unroll
    for (int t = 0; t < TPW; ++t) {
        float* cur = (t & 1) ? b1 : b0;
        float* nxt = (t & 1) ? b0 : b1;

        // (1) issue next token's global loads EARLY (latency hides under compute)
        float4 n0, n1, n2, m0, m1, m2, m3;
        if (t + 1 < TPW) {
            const float4* G2n = (const float4*)(g23 + (idxs[t + 1] % 400) * 768);
            n0 = G2n[lane]; n1 = G2n[lane + 64]; n2 = G2n[lane + 128];
            const float4* g1n = (const float4*)(g01 + (idxs[t + 1] / 400) * 256 + a * 16);
            m0 = g1n[0]; m1 = g1n[1]; m2 = g1n[2]; m3 = g1n[3];
        }

        // (2) compute token t from LDS (48 broadcast ds_read_b128, conflict-free)
        const float* cq = cur + q * 4;
        float4 sarr[4] = {s0, s1, s2, s3};
        float4 acc0 = {0.f,0.f,0.f,0.f}, acc1 = {0.f,0.f,0.f,0.f}, acc2 = {0.f,0.f,0.f,0.f};
#pragma unroll
        for (int rr = 0; rr < 4; ++rr) {
#pragma unroll
            for (int c = 0; c < 4; ++c) {
                const int r2 = rr * 4 + c;
                float4 v0 = *(const float4*)(cq + r2 * 48);
                float4 v1 = *(const float4*)(cq + r2 * 48 + 16);
                float4 v2 = *(const float4*)(cq + r2 * 48 + 32);
                float sv = (c == 0) ? sarr[rr].x : (c == 1) ? sarr[rr].y
                         : (c == 2) ? sarr[rr].z : sarr[rr].w;
                FMA4(acc0, sv, v0);
                FMA4(acc1, sv, v1);
                FMA4(acc2, sv, v2);
            }
        }

        // (3) store token t with NON-TEMPORAL stores (bypass L2; output is
        // never re-read, and this keeps the 1.2MB G23 table L2-resident)
        float4* o4 = (float4*)(out + (size_t)(tok0 + t) * 768);
        NTSTORE(acc0, o4 + a * 12 + q);
        NTSTORE(acc1, o4 + a * 12 + q + 4);
        NTSTORE(acc2, o4 + a * 12 + q + 8);

        // (4) write next token's slice into the other buffer LATE
        if (t + 1 < TPW) {
            ((float4*)nxt)[lane] = n0;
            ((float4*)nxt)[lane + 64] = n1;
            ((float4*)nxt)[lane + 128] = n2;
            s0 = m0; s1 = m1; s2 = m2; s3 = m3;
        }
    }
}

// ---- fallback ----
__global__ void te_direct(const int* __restrict__ x,
                          const float* __restrict__ core0,
                          const float* __restrict__ core1,
                          const float* __restrict__ core2,
                          const float* __restrict__ core3,
                          float* __restrict__ out) {
    int tok = blockIdx.x;
    int lane = threadIdx.x;
    int idx = x[tok];
    int d0 = idx / 4000;
    int rem = idx - d0 * 4000;
    int d1 = rem / 400;
    rem -= d1 * 400;
    int d2 = rem / 20;
    int d3 = rem - d2 * 20;
    float* o = out + (size_t)tok * 768;
    for (int p = 0; p < 3; ++p) {
        int base = (p * 64 + lane) * 4;
        int a = base / 48;
        int mc = base - a * 48;
        int a0 = a >> 2, m1 = a & 3;
        float s[16];
#pragma unroll
        for (int r2 = 0; r2 < 16; ++r2) {
            float acc = 0.f;
            for (int r1 = 0; r1 < 16; ++r1)
                acc += core0[(d0 * 4 + a0) * 16 + r1] *
                       core1[((r1 * 10 + d1) * 4 + m1) * 16 + r2];
            s[r2] = acc;
        }
        float4 accv = {0.f, 0.f, 0.f, 0.f};
        float* accp = (float*)&accv;
        for (int j = 0; j < 4; ++j) {
            int mcj = mc + j;
            int m2 = mcj >> 3, m3 = mcj & 7;
            float tt = 0.f;
            for (int r2 = 0; r2 < 16; ++r2) {
                float g = 0.f;
                for (int r3 = 0; r3 < 16; ++r3)
                    g += core2[((r2 * 20 + d2) * 6 + m2) * 16 + r3] *
                         core3[(r3 * 20 + d3) * 8 + m3];
                tt += s[r2] * g;
            }
            accp[j] = tt;
        }
        *(float4*)(o + base) = accv;
    }
}

extern "C" void kernel_launch(void* const* d_in, const int* in_sizes, int n_in,
                              void* d_out, int out_size, void* d_ws, size_t ws_size,
                              hipStream_t stream) {
    const int*   x     = (const int*)d_in[0];
    const float* core0 = (const float*)d_in[1];
    const float* core1 = (const float*)d_in[2];
    const float* core2 = (const float*)d_in[3];
    const float* core3 = (const float*)d_in[4];
    float* out = (float*)d_out;

    if (ws_size >= (size_t)TBL_BYTES) {
        float* g01 = (float*)d_ws;
        float* g23 = (float*)((char*)d_ws + G01_BYTES);
        build_tables<<<480, 256, 0, stream>>>(core0, core1, core2, core3, g01, g23);
        // 1024 blocks x 4 waves x 8 tokens = 32768 exactly
        te_stream<<<NTOK / (4 * TPW), 256, 0, stream>>>(x, g01, g23, out);
    } else {
        te_direct<<<NTOK, 64, 0, stream>>>(x, core0, core1, core2, core3, out);
    }
}

// Round 7
// 29.668 us; speedup vs baseline: 1.2439x; 1.2334x over previous
//
#include <hip/hip_runtime.h>

// Tensorized (tensor-train) embedding. vocab 32000 = 8*10*20*20, out 768,
// ranks (1,16,16,16,1), B = 32768 tokens, fp32 out.
//
// Per token: out[a][mc] = sum_r2 G01[c01][a][r2] * G23[c23][r2][mc]
//   (c01 = idx/400, c23 = idx%400) -- a 16x16 @ 16x48 matmul.
// Done as 3x mfma_f32_16x16x32_f16 (K zero-padded to 32), computing the
// TRANSPOSED tile (A = G2^T 16-col chunk, B = G1^T) so each lane's 4 accs
// are 4 consecutive mc of one output row -> 3 coalesced float4 stores.
// Tables are precomputed in f16 *fragment order*, so per token each lane
// issues just 4 coalesced 16B loads + 3 MFMAs + 3 stores. Zero LDS in the
// hot kernel (R4-R6 were LDS-crossbar-bound: 48 ds_read_b128/token with
// 16-way broadcast redundancy ~= 25 us/CU).
//
// Fragment maps (gfx950, m89-verified D; A/B standard, k-permutation
// cancels since both fragments are built with the same k map):
//   A[m][k]: lane l holds m = l&15, k = (l>>4)*8+j (j=0..7; k>=16 -> 0)
//   B[k][n]: lane l holds n = l&15, same k map
//   D[m][n]: lane l reg r holds m = (l>>4)*4+r, n = l&15

#define NTOK 32768
#define TPW  8
#define G2F_BYTES (400 * 3 * 64 * 16)         // 1228800
#define G1F_BYTES (80 * 64 * 16)              // 81920
#define TBL_BYTES (G2F_BYTES + G1F_BYTES)     // 1310720

typedef _Float16 f16x8 __attribute__((ext_vector_type(8)));
typedef float f32x4 __attribute__((ext_vector_type(4)));

__device__ inline unsigned pack2(float x, float y) {
    _Float16 hx = (_Float16)x, hy = (_Float16)y;
    unsigned short ux = __builtin_bit_cast(unsigned short, hx);
    unsigned short uy = __builtin_bit_cast(unsigned short, hy);
    return (unsigned)ux | ((unsigned)uy << 16);
}

// ---- kernel A: build f16 fragment tables (480 blocks, R4-style reads) ----
__global__ __launch_bounds__(256) void build_frag_tables(const float* __restrict__ core0,
                                                         const float* __restrict__ core1,
                                                         const float* __restrict__ core2,
                                                         const float* __restrict__ core3,
                                                         unsigned* __restrict__ g2f,
                                                         unsigned* __restrict__ g1f) {
    __shared__ float lds[768];
    int b = blockIdx.x, t = threadIdx.x;
    if (b < 400) {                          // G23 combo c23 = d2*20+d3
        int d2 = b / 20, d3 = b % 20;
#pragma unroll
        for (int i = 0; i < 3; ++i) {
            int f = t + i * 256;            // f = r2*48 + mc
            int r2 = f / 48, mc = f - r2 * 48;
            int m2 = mc >> 3, m3 = mc & 7;
            float acc = 0.f;
#pragma unroll
            for (int r3 = 0; r3 < 16; ++r3)
                acc += core2[((r2 * 20 + d2) * 6 + m2) * 16 + r3] *   // [16,20,6,16]
                       core3[(r3 * 20 + d3) * 8 + m3];                // [16,20,8,1]
            lds[f] = acc;
        }
        __syncthreads();
        // emit fragment pairs: per (c23,p): 64 lanes x 4 u32 (= 8 f16)
        int l = t >> 2, jp = t & 3;
        int k0 = ((l >> 4) << 3) + jp * 2;  // even; k0<16 <=> k0+1<16
        int mcl = l & 15;
        bool valid = k0 < 16;
#pragma unroll
        for (int p = 0; p < 3; ++p) {
            int mc = p * 16 + mcl;
            float v0 = valid ? lds[k0 * 48 + mc] : 0.f;
            float v1 = valid ? lds[(k0 + 1) * 48 + mc] : 0.f;
            g2f[(b * 3 + p) * 256 + t] = pack2(v0, v1);
        }
    } else {                                // G01 combo c01 = d0*10+d1
        int combo = b - 400;                // 0..79
        int d0 = combo / 10, d1 = combo % 10;
        int a = t >> 4, r2 = t & 15;
        int a0 = a >> 2, m1 = a & 3;
        float acc = 0.f;
#pragma unroll
        for (int r1 = 0; r1 < 16; ++r1)
            acc += core0[(d0 * 4 + a0) * 16 + r1] *                   // [1,8,4,16]
                   core1[((r1 * 10 + d1) * 4 + m1) * 16 + r2];        // [16,10,4,16]
        lds[t] = acc;                       // lds[a*16 + r2]
        __syncthreads();
        int l = t >> 2, jp = t & 3;
        int k0 = ((l >> 4) << 3) + jp * 2;
        int al = l & 15;
        bool valid = k0 < 16;
        float v0 = valid ? lds[al * 16 + k0] : 0.f;
        float v1 = valid ? lds[al * 16 + k0 + 1] : 0.f;
        g1f[combo * 256 + t] = pack2(v0, v1);
    }
}

// ---- kernel B: MFMA main, zero LDS ----
__global__ __launch_bounds__(256) void te_mfma(const int* __restrict__ x,
                                               const f16x8* __restrict__ g2f,
                                               const f16x8* __restrict__ g1f,
                                               float* __restrict__ out) {
    const int wave = threadIdx.x >> 6, lane = threadIdx.x & 63;
    const int tok0 = (blockIdx.x * 4 + wave) * TPW;

    int4 xa = ((const int4*)(x + tok0))[0];
    int4 xb = ((const int4*)(x + tok0))[1];
    int idxs[TPW] = {xa.x, xa.y, xa.z, xa.w, xb.x, xb.y, xb.z, xb.w};

    f16x8 A0, A1, A2, B;
    {
        int id = idxs[0];
        const f16x8* ap = g2f + (size_t)(id % 400) * 192 + lane;
        A0 = ap[0]; A1 = ap[64]; A2 = ap[128];
        B = g1f[(id / 400) * 64 + lane];
    }
    const f32x4 z = {0.f, 0.f, 0.f, 0.f};
    float* obase = out + (size_t)tok0 * 768 + (lane & 15) * 48 + ((lane >> 4) << 2);

#pragma unroll
    for (int t = 0; t < TPW; ++t) {
        // prefetch next token's fragments (hides L2 latency under MFMA+stores)
        int tn = (t + 1 < TPW) ? t + 1 : t;
        int id = idxs[tn];
        const f16x8* ap = g2f + (size_t)(id % 400) * 192 + lane;
        f16x8 nA0 = ap[0], nA1 = ap[64], nA2 = ap[128];
        f16x8 nB = g1f[(id / 400) * 64 + lane];

        f32x4 d0 = __builtin_amdgcn_mfma_f32_16x16x32_f16(A0, B, z, 0, 0, 0);
        f32x4 d1 = __builtin_amdgcn_mfma_f32_16x16x32_f16(A1, B, z, 0, 0, 0);
        f32x4 d2 = __builtin_amdgcn_mfma_f32_16x16x32_f16(A2, B, z, 0, 0, 0);

        float* o = obase + t * 768;
        *(f32x4*)(o)      = d0;             // p=0: mc + 0
        *(f32x4*)(o + 16) = d1;             // p=1: mc + 16
        *(f32x4*)(o + 32) = d2;             // p=2: mc + 32

        A0 = nA0; A1 = nA1; A2 = nA2; B = nB;
    }
}

// ---- fallback (tiny ws): direct evaluation ----
__global__ void te_direct(const int* __restrict__ x,
                          const float* __restrict__ core0,
                          const float* __restrict__ core1,
                          const float* __restrict__ core2,
                          const float* __restrict__ core3,
                          float* __restrict__ out) {
    int tok = blockIdx.x;
    int lane = threadIdx.x;
    int idx = x[tok];
    int d0 = idx / 4000;
    int rem = idx - d0 * 4000;
    int d1 = rem / 400;
    rem -= d1 * 400;
    int d2 = rem / 20;
    int d3 = rem - d2 * 20;
    float* o = out + (size_t)tok * 768;
    for (int p = 0; p < 3; ++p) {
        int base = (p * 64 + lane) * 4;
        int a = base / 48;
        int mc = base - a * 48;
        int a0 = a >> 2, m1 = a & 3;
        float s[16];
#pragma unroll
        for (int r2 = 0; r2 < 16; ++r2) {
            float acc = 0.f;
            for (int r1 = 0; r1 < 16; ++r1)
                acc += core0[(d0 * 4 + a0) * 16 + r1] *
                       core1[((r1 * 10 + d1) * 4 + m1) * 16 + r2];
            s[r2] = acc;
        }
        float4 accv = {0.f, 0.f, 0.f, 0.f};
        float* accp = (float*)&accv;
        for (int j = 0; j < 4; ++j) {
            int mcj = mc + j;
            int m2 = mcj >> 3, m3 = mcj & 7;
            float tt = 0.f;
            for (int r2 = 0; r2 < 16; ++r2) {
                float g = 0.f;
                for (int r3 = 0; r3 < 16; ++r3)
                    g += core2[((r2 * 20 + d2) * 6 + m2) * 16 + r3] *
                         core3[(r3 * 20 + d3) * 8 + m3];
                tt += s[r2] * g;
            }
            accp[j] = tt;
        }
        *(float4*)(o + base) = accv;
    }
}

extern "C" void kernel_launch(void* const* d_in, const int* in_sizes, int n_in,
                              void* d_out, int out_size, void* d_ws, size_t ws_size,
                              hipStream_t stream) {
    const int*   x     = (const int*)d_in[0];
    const float* core0 = (const float*)d_in[1];
    const float* core1 = (const float*)d_in[2];
    const float* core2 = (const float*)d_in[3];
    const float* core3 = (const float*)d_in[4];
    float* out = (float*)d_out;

    if (ws_size >= (size_t)TBL_BYTES) {
        unsigned* g2f = (unsigned*)d_ws;
        unsigned* g1f = (unsigned*)((char*)d_ws + G2F_BYTES);
        build_frag_tables<<<480, 256, 0, stream>>>(core0, core1, core2, core3,
                                                   g2f, g1f);
        // 1024 blocks x 4 waves x 8 tokens = 32768 exactly
        te_mfma<<<NTOK / (4 * TPW), 256, 0, stream>>>(x, (const f16x8*)g2f,
                                                      (const f16x8*)g1f, out);
    } else {
        te_direct<<<NTOK, 64, 0, stream>>>(x, core0, core1, core2, core3, out);
    }
}